// Round 8
// baseline (348.947 us; speedup 1.0000x reference)
//
#include <hip/hip_runtime.h>
#include <hip/hip_bf16.h>
#include <stdint.h>

#define BB 2
#define SS 2048
#define HH 1024
#define NHEAD 16
#define NKVH 8
#define DD 128
#define MM (BB*SS)   // 4096 rows

typedef __bf16 bf16_t;
typedef __bf16 bf16x8 __attribute__((ext_vector_type(8)));
typedef __bf16 bf16x4 __attribute__((ext_vector_type(4)));
typedef float  f32x4  __attribute__((ext_vector_type(4)));

// ---------------- fused fp32 -> bf16 convert for all 5 inputs ----------------
// region boundaries in float4 units:
// hidden 1048576 | wq 524288 | wk 262144 | wv 262144 | wo 524288  (total 2621440)
__global__ __launch_bounds__(256) void k_cvt_all(
    const float* __restrict__ h, const float* __restrict__ wq,
    const float* __restrict__ wk, const float* __restrict__ wv,
    const float* __restrict__ wo, bf16_t* __restrict__ hbf,
    bf16_t* __restrict__ wqkv, bf16_t* __restrict__ wob) {
  int i = blockIdx.x * 256 + threadIdx.x;
  const int stride = gridDim.x * 256;
  for (; i < 2621440; i += stride) {
    const float* src; bf16_t* dst; int off;
    if (i < 1048576)      { src = h;  dst = hbf;            off = i; }
    else if (i < 1572864) { src = wq; dst = wqkv;           off = i - 1048576; }
    else if (i < 1835008) { src = wk; dst = wqkv + 2097152; off = i - 1572864; }
    else if (i < 2097152) { src = wv; dst = wqkv + 3145728; off = i - 1835008; }
    else                  { src = wo; dst = wob;            off = i - 2097152; }
    float4 v = reinterpret_cast<const float4*>(src)[off];
    bf16x4 o;
    o[0] = (bf16_t)v.x; o[1] = (bf16_t)v.y; o[2] = (bf16_t)v.z; o[3] = (bf16_t)v.w;
    reinterpret_cast<bf16x4*>(dst)[off] = o;
  }
}

// ---------------- zero fp32 buffer (graph-capture-safe) ----------------
__global__ __launch_bounds__(256) void k_zero(float4* __restrict__ p, int n4) {
  int i = blockIdx.x * 256 + threadIdx.x;
  const int stride = gridDim.x * 256;
  const float4 z = make_float4(0.f, 0.f, 0.f, 0.f);
  for (; i < n4; i += stride) p[i] = z;
}

// ---------------- GEMM: C[M,N] (+)= A[M,LD-slice] * B[N,LD-slice]^T ----------------
// m97 structure: 128x128 tile, BK=64, 4 waves (2x2), global_load_lds width-16
// staging into linear LDS [128][64], 2-barrier K-loop. blockIdx.z = K-split
// index (Ksplit cols each); ATOM=1 -> fp32 atomicAdd epilogue (needs k_zero'd C).
template <typename CT, int ATOM>
__global__ __launch_bounds__(256, 3) void k_gemm_lds(
    const bf16_t* __restrict__ A, const bf16_t* __restrict__ Bm,
    CT* __restrict__ C, int M, int N, int LD, int Ksplit) {
  __shared__ bf16_t As[128 * 64];   // 16 KB, linear (lane-order contiguous)
  __shared__ bf16_t Bs[128 * 64];   // 16 KB
  const int t = threadIdx.x;
  const int lane = t & 63, wave = t >> 6;
  const int c = lane & 15, g = lane >> 4;
  const int wm = wave >> 1, wn = wave & 1;
  const long m0 = (long)blockIdx.y * 128;
  const long n0 = (long)blockIdx.x * 128;
  const long kbase = (long)blockIdx.z * Ksplit;
  const int srow = t >> 3, sc8 = t & 7;   // staging: row = i*32+srow, col8 = sc8

  const bf16_t* Ag = A + (m0 + srow) * LD + kbase + sc8 * 8;
  const bf16_t* Bg = Bm + (n0 + srow) * LD + kbase + sc8 * 8;

  f32x4 acc[4][4] = {};
  const int nk = Ksplit >> 6;
  for (int kt = 0; kt < nk; ++kt) {
    const long koff = (long)kt * 64;
    __syncthreads();   // previous tile's compute done before overwrite
#pragma unroll
    for (int i = 0; i < 4; ++i) {
      __builtin_amdgcn_global_load_lds(
          (const __attribute__((address_space(1))) uint32_t*)(const void*)(Ag + (long)i * 32 * LD + koff),
          (__attribute__((address_space(3))) uint32_t*)(void*)(&As[(i * 256 + t) * 8]),
          16, 0, 0);
      __builtin_amdgcn_global_load_lds(
          (const __attribute__((address_space(1))) uint32_t*)(const void*)(Bg + (long)i * 32 * LD + koff),
          (__attribute__((address_space(3))) uint32_t*)(void*)(&Bs[(i * 256 + t) * 8]),
          16, 0, 0);
    }
    __syncthreads();   // compiler drains vmcnt(0) before this barrier
#pragma unroll
    for (int kk = 0; kk < 2; ++kk) {
      bf16x8 af[4], bfr[4];
#pragma unroll
      for (int mi = 0; mi < 4; ++mi)
        af[mi] = *reinterpret_cast<const bf16x8*>(
            &As[(wm * 64 + mi * 16 + c) * 64 + kk * 32 + g * 8]);
#pragma unroll
      for (int ni = 0; ni < 4; ++ni)
        bfr[ni] = *reinterpret_cast<const bf16x8*>(
            &Bs[(wn * 64 + ni * 16 + c) * 64 + kk * 32 + g * 8]);
#pragma unroll
      for (int mi = 0; mi < 4; ++mi)
#pragma unroll
        for (int ni = 0; ni < 4; ++ni)
          acc[mi][ni] = __builtin_amdgcn_mfma_f32_16x16x32_bf16(
              af[mi], bfr[ni], acc[mi][ni], 0, 0, 0);
    }
  }
  // C/D layout: col = lane&15, row = (lane>>4)*4 + r
#pragma unroll
  for (int mi = 0; mi < 4; ++mi)
#pragma unroll
    for (int ni = 0; ni < 4; ++ni)
#pragma unroll
      for (int r = 0; r < 4; ++r) {
        long m = m0 + wm * 64 + mi * 16 + 4 * g + r;
        long n = n0 + wn * 64 + ni * 16 + c;
        if (ATOM) atomicAdd((float*)&C[m * N + n], acc[mi][ni][r]);
        else      C[m * N + n] = (CT)acc[mi][ni][r];
      }
}

// ---------------- fused RMSNorm + RoPE + [B,S,h,D]->[B,h,S,D] transpose ----------------
// raw rows have stride rstride (fused QKV output); head h at col offset h*DD.
__global__ __launch_bounds__(256) void k_nr(
    const bf16_t* __restrict__ raw, bf16_t* __restrict__ outp,
    const float* __restrict__ w, const float* __restrict__ cosb,
    const float* __restrict__ sinb, int nheads, int rstride) {
  const int wid = (blockIdx.x * 256 + threadIdx.x) >> 6;
  const int lane = threadIdx.x & 63;
  const int h = wid % nheads;
  const int bs = wid / nheads;           // b*S + s
  const int b = bs / SS, s = bs - b * SS;
  const bf16_t* rp = raw + (long)bs * rstride + h * DD;
  float x0 = (float)rp[lane];
  float x1 = (float)rp[lane + 64];
  float ssq = x0 * x0 + x1 * x1;
#pragma unroll
  for (int m = 1; m < 64; m <<= 1) ssq += __shfl_xor(ssq, m);
  const float rs = rsqrtf(ssq * (1.0f / DD) + 1e-6f);
  const float xn0 = x0 * rs * w[lane];
  const float xn1 = x1 * rs * w[lane + 64];
  const float cc = cosb[(long)bs * DD + lane];   // cos[d+64]==cos[d]
  const float sn = sinb[(long)bs * DD + lane];
  bf16_t o0 = (bf16_t)(xn0 * cc - xn1 * sn);
  bf16_t o1 = (bf16_t)(xn1 * cc + xn0 * sn);
  bf16_t* op = outp + (((long)b * nheads + h) * SS + s) * DD;
  op[lane] = o0;
  op[lane + 64] = o1;
}

// ---------------- V transpose: qkvr V-cols [B,S,(kvh,d)] -> V^T [B,kvh,D,S] ----------------
// per block: 64 s x 128 d tile; coalesced in, LDS transpose, coalesced out.
__global__ __launch_bounds__(256) void k_vt(const bf16_t* __restrict__ src,
                                            bf16_t* __restrict__ vt) {
  __shared__ bf16_t Ls[64 * 136];   // pad 128->136
  const int t = threadIdx.x;
  const int s0 = blockIdx.x * 64;
  const int kvh = blockIdx.y;
  const int b = blockIdx.z;
  const bf16_t* ip = src + ((long)b * SS) * 4096 + 3072 + kvh * DD;
#pragma unroll
  for (int i = 0; i < 4; ++i) {
    const int cid = i * 256 + t;
    const int sr = cid >> 4, c8 = cid & 15;
    *reinterpret_cast<uint4*>(&Ls[sr * 136 + c8 * 8]) =
        *reinterpret_cast<const uint4*>(ip + (long)(s0 + sr) * 4096 + c8 * 8);
  }
  __syncthreads();
  const int d = t >> 1, sh = (t & 1) * 32;
  bf16_t* op = vt + (((long)b * NKVH + kvh) * DD + d) * SS + s0 + sh;
  bf16_t buf[32];
#pragma unroll
  for (int j = 0; j < 32; ++j) buf[j] = Ls[(sh + j) * 136 + d];
#pragma unroll
  for (int q = 0; q < 4; ++q)
    reinterpret_cast<uint4*>(op)[q] = reinterpret_cast<uint4*>(buf)[q];
}

// ---------------- causal GQA flash attention v4 ----------------
// 4 waves x 32 q rows (Q-tile 128); KVBLK=64. K: [64][128] XOR-swizzled.
// V: pre-transposed global V^T -> Vs[128 d][64 k] XOR-swizzled (no scatter).
// P^T: per-wave XOR-swizzled LDS.
__global__ __launch_bounds__(256, 2) void k_attn(
    const bf16_t* __restrict__ Qh, const bf16_t* __restrict__ Kh,
    const bf16_t* __restrict__ VT, bf16_t* __restrict__ AO) {
  __shared__ bf16_t Ks[64 * 128];          // 16 KB, swizzled
  __shared__ bf16_t Vs[128 * 64];          // 16 KB, V^T rows, swizzled
  __shared__ bf16_t Pq[4 * 2 * 16 * 64];   // 16 KB, per-wave P
  const int t = threadIdx.x;
  const int lane = t & 63, wave = t >> 6;
  const int c = lane & 15, g = lane >> 4;

  // grid remap: xcd-grouped heads + complementary qt pairing (id, id+256)
  const int id = blockIdx.x;
  const int xcd = id & 7, j2 = (id >> 3) & 3, qt8 = (id >> 5) & 7, half = id >> 8;
  const int qt = half ? (15 - qt8) : qt8;
  const int hb = xcd * 4 + j2;
  const int h = hb & 15, b = hb >> 4;
  const int kvh = h >> 1;                  // GQA n_rep = 2

  const int qbase = qt * 128 + wave * 32;
  const int qg0 = qbase + c, qg1 = qbase + 16 + c;

  const bf16_t* qp = Qh + (((long)b * NHEAD + h) * SS) * DD;
  bf16x8 qf[2][4];
#pragma unroll
  for (int qc = 0; qc < 2; ++qc)
#pragma unroll
    for (int kb = 0; kb < 4; ++kb)
      qf[qc][kb] = *reinterpret_cast<const bf16x8*>(
          qp + (long)(qbase + qc * 16 + c) * DD + kb * 32 + g * 8);

  const bf16_t* kp = Kh + ((long)b * NKVH + kvh) * SS * DD;
  const bf16_t* vtp = VT + ((long)b * NKVH + kvh) * DD * SS;   // [D][S]

  f32x4 o[8][2] = {};
  float mrow[2] = {-1e30f, -1e30f}, lrow[2] = {0.f, 0.f};
  const int srow2 = t >> 4, sc16 = t & 15;
  const int kv_end = qt * 128 + 128;
  const float scale = 0.08838834764831845f;   // 1/sqrt(128)
  const int c7x8 = 8 * (c & 7);

  for (int kv0 = 0; kv0 < kv_end; kv0 += 64) {
    __syncthreads();
    // stage K [64 keys][128 d], XOR-swizzled, b128
#pragma unroll
    for (int rr = 0; rr < 4; ++rr) {
      const int row = srow2 + rr * 16;
      uint4 kvv = *reinterpret_cast<const uint4*>(kp + (long)(kv0 + row) * DD + sc16 * 8);
      *reinterpret_cast<uint4*>(&Ks[row * 128 + 8 * (sc16 ^ (row & 7))]) = kvv;
    }
    // stage V^T [128 d][64 keys], XOR-swizzled, b128 (coalesced rows of V^T)
#pragma unroll
    for (int i = 0; i < 4; ++i) {
      const int cid = i * 256 + t;
      const int d = cid >> 3, c8 = cid & 7;
      uint4 vv = *reinterpret_cast<const uint4*>(vtp + (long)d * SS + kv0 + c8 * 8);
      *reinterpret_cast<uint4*>(&Vs[d * 64 + 8 * (c8 ^ (d & 7))]) = vv;
    }
    __syncthreads();

    if (kv0 <= qbase + 31) {      // wave-uniform: skip fully-masked tiles
      // ---- S^T = K·Q^T ----
      f32x4 s[2][4] = {};
#pragma unroll
      for (int kb = 0; kb < 4; ++kb) {
        bf16x8 kf[4];
#pragma unroll
        for (int kc = 0; kc < 4; ++kc)
          kf[kc] = *reinterpret_cast<const bf16x8*>(
              &Ks[(kc * 16 + c) * 128 + 8 * (((kb << 2) | g) ^ (c & 7))]);
#pragma unroll
        for (int qc = 0; qc < 2; ++qc)
#pragma unroll
          for (int kc = 0; kc < 4; ++kc)
            s[qc][kc] = __builtin_amdgcn_mfma_f32_16x16x32_bf16(
                kf[kc], qf[qc][kb], s[qc][kc], 0, 0, 0);
      }
      // ---- online softmax (per qc), P^T -> per-wave LDS ----
#pragma unroll
      for (int qc = 0; qc < 2; ++qc) {
        const int qg = qc ? qg1 : qg0;
        float sv[16];
#pragma unroll
        for (int i = 0; i < 16; ++i) {
          const int key = kv0 + (i >> 2) * 16 + 4 * g + (i & 3);
          const float x = s[qc][i >> 2][i & 3];
          sv[i] = (key <= qg) ? x * scale : -1e30f;
        }
        float vm = sv[0];
#pragma unroll
        for (int i = 1; i < 16; ++i) vm = fmaxf(vm, sv[i]);
        vm = fmaxf(vm, __shfl_xor(vm, 16));
        vm = fmaxf(vm, __shfl_xor(vm, 32));
        const float mnew = fmaxf(mrow[qc], vm);
        const float alpha = __expf(mrow[qc] - mnew);
        float p[16], ps = 0.f;
#pragma unroll
        for (int i = 0; i < 16; ++i) { p[i] = __expf(sv[i] - mnew); ps += p[i]; }
        ps += __shfl_xor(ps, 16);
        ps += __shfl_xor(ps, 32);
        lrow[qc] = lrow[qc] * alpha + ps;
        mrow[qc] = mnew;
#pragma unroll
        for (int dt = 0; dt < 8; ++dt) o[dt][qc] = o[dt][qc] * alpha;
#pragma unroll
        for (int kc = 0; kc < 4; ++kc) {
          bf16x4 pk;
#pragma unroll
          for (int r = 0; r < 4; ++r) pk[r] = (bf16_t)p[kc * 4 + r];
          *reinterpret_cast<bf16x4*>(
              &Pq[((wave * 2 + qc) * 16 + c) * 64 + ((kc * 16 + 4 * g) ^ c7x8)]) = pk;
        }
      }
      // ---- O^T += V^T · P^T ----
#pragma unroll
      for (int kc2 = 0; kc2 < 2; ++kc2) {
        bf16x8 pf[2];
#pragma unroll
        for (int qc = 0; qc < 2; ++qc)
          pf[qc] = *reinterpret_cast<const bf16x8*>(
              &Pq[((wave * 2 + qc) * 16 + c) * 64 + ((kc2 * 32 + g * 8) ^ c7x8)]);
#pragma unroll
        for (int dt = 0; dt < 8; ++dt) {
          const int dr = dt * 16 + c;
          bf16x8 vf = *reinterpret_cast<const bf16x8*>(
              &Vs[dr * 64 + 8 * ((kc2 * 4 + g) ^ (c & 7))]);
#pragma unroll
          for (int qc = 0; qc < 2; ++qc)
            o[dt][qc] = __builtin_amdgcn_mfma_f32_16x16x32_bf16(
                vf, pf[qc], o[dt][qc], 0, 0, 0);
        }
      }
    }
  }
  // ---- epilogue ----
#pragma unroll
  for (int qc = 0; qc < 2; ++qc) {
    const float linv = 1.0f / lrow[qc];
    bf16_t* aop = AO + ((long)(b * SS) + qbase + qc * 16 + c) * (NHEAD * DD) + h * DD;
#pragma unroll
    for (int dt = 0; dt < 8; ++dt) {
      bf16x4 ov;
#pragma unroll
      for (int r = 0; r < 4; ++r) ov[r] = (bf16_t)(o[dt][qc][r] * linv);
      *reinterpret_cast<bf16x4*>(aop + dt * 16 + 4 * g) = ov;
    }
  }
}

// ---------------- launch ----------------
extern "C" void kernel_launch(void* const* d_in, const int* in_sizes, int n_in,
                              void* d_out, int out_size, void* d_ws, size_t ws_size,
                              hipStream_t stream) {
  const float* hidden = (const float*)d_in[0];
  const float* cosb   = (const float*)d_in[1];
  const float* sinb   = (const float*)d_in[2];
  const float* Wq     = (const float*)d_in[3];
  const float* Wk     = (const float*)d_in[4];
  const float* Wv     = (const float*)d_in[5];
  const float* Wo     = (const float*)d_in[6];
  const float* qnw    = (const float*)d_in[7];
  const float* knw    = (const float*)d_in[8];
  float* outp = (float*)d_out;
  char* ws = (char*)d_ws;
  const size_t MB = 1024 * 1024;
  bf16_t* hbf   = (bf16_t*)(ws + 0);        //  8 MB  hidden bf16 [4096][1024]
  bf16_t* wqkv  = (bf16_t*)(ws + 8 * MB);   //  8 MB  [Wq;Wk;Wv] as [4096][1024]
  bf16_t* wob   = (bf16_t*)(ws + 16 * MB);  //  4 MB
  bf16_t* qkvr  = (bf16_t*)(ws + 20 * MB);  // 32 MB  [4096][4096] fused QKV out
  bf16_t* qn    = (bf16_t*)(ws + 52 * MB);  // 16 MB  [B,NH,S,D]
  bf16_t* kn    = (bf16_t*)(ws + 68 * MB);  //  8 MB  [B,NKV,S,D]
  bf16_t* vt    = (bf16_t*)(ws + 76 * MB);  //  8 MB  V^T [B,NKV,D,S]  (total 84 MB)
  bf16_t* ao    = qkvr;                     // reuse (16 MB needed)

  k_cvt_all<<<2048, 256, 0, stream>>>(hidden, Wq, Wk, Wv, Wo, hbf, wqkv, wob);

  // fused QKV projection: C[4096][4096] = hbf[4096][1024] x wqkv^T
  k_gemm_lds<bf16_t, 0><<<dim3(32, 32, 1), 256, 0, stream>>>(
      hbf, wqkv, qkvr, MM, 4096, 1024, 1024);

  k_nr<<<MM * NHEAD / 4, 256, 0, stream>>>(qkvr, qn, qnw, cosb, sinb, NHEAD, 4096);
  k_nr<<<MM * NKVH / 4, 256, 0, stream>>>(qkvr + 2048, kn, knw, cosb, sinb, NKVH, 4096);
  k_vt<<<dim3(32, 8, 2), 256, 0, stream>>>(qkvr, vt);

  k_attn<<<dim3(512), 256, 0, stream>>>(qn, kn, vt, ao);

  // output projection: split-K=2, fp32 atomic accumulate
  k_zero<<<1024, 256, 0, stream>>>((float4*)outp, MM * 1024 / 4);
  k_gemm_lds<float, 1><<<dim3(8, 32, 2), 256, 0, stream>>>(
      ao, wob, outp, MM, 1024, 2048, 1024);
}

// Round 10
// 335.680 us; speedup vs baseline: 1.0395x; 1.0395x over previous
//
#include <hip/hip_runtime.h>
#include <hip/hip_bf16.h>
#include <stdint.h>

#define BB 2
#define SS 2048
#define HH 1024
#define NHEAD 16
#define NKVH 8
#define DD 128
#define MM (BB*SS)   // 4096 rows

typedef __bf16 bf16_t;
typedef __bf16 bf16x8 __attribute__((ext_vector_type(8)));
typedef __bf16 bf16x4 __attribute__((ext_vector_type(4)));
typedef float  f32x4  __attribute__((ext_vector_type(4)));

// ---------------- fused fp32 -> bf16 convert for all 5 inputs ----------------
__global__ __launch_bounds__(256) void k_cvt_all(
    const float* __restrict__ h, const float* __restrict__ wq,
    const float* __restrict__ wk, const float* __restrict__ wv,
    const float* __restrict__ wo, bf16_t* __restrict__ hbf,
    bf16_t* __restrict__ wqkv, bf16_t* __restrict__ wob) {
  int i = blockIdx.x * 256 + threadIdx.x;
  const int stride = gridDim.x * 256;
  for (; i < 2621440; i += stride) {
    const float* src; bf16_t* dst; int off;
    if (i < 1048576)      { src = h;  dst = hbf;            off = i; }
    else if (i < 1572864) { src = wq; dst = wqkv;           off = i - 1048576; }
    else if (i < 1835008) { src = wk; dst = wqkv + 2097152; off = i - 1572864; }
    else if (i < 2097152) { src = wv; dst = wqkv + 3145728; off = i - 1835008; }
    else                  { src = wo; dst = wob;            off = i - 2097152; }
    float4 v = reinterpret_cast<const float4*>(src)[off];
    bf16x4 o;
    o[0] = (bf16_t)v.x; o[1] = (bf16_t)v.y; o[2] = (bf16_t)v.z; o[3] = (bf16_t)v.w;
    reinterpret_cast<bf16x4*>(dst)[off] = o;
  }
}

// ---------------- GEMM: C[M,N] = A[M,LD] * B[N,LD]^T  (bf16 in, CT out) ----------------
// m97 structure: 128x128 tile, BK=64, 4 waves (2x2), global_load_lds width-16
// staging into linear LDS [128][64], 2-barrier K-loop.
template <typename CT>
__global__ __launch_bounds__(256, 3) void k_gemm_lds(
    const bf16_t* __restrict__ A, const bf16_t* __restrict__ Bm,
    CT* __restrict__ C, int M, int N, int LD) {
  __shared__ bf16_t As[128 * 64];   // 16 KB, linear (lane-order contiguous)
  __shared__ bf16_t Bs[128 * 64];   // 16 KB
  const int t = threadIdx.x;
  const int lane = t & 63, wave = t >> 6;
  const int c = lane & 15, g = lane >> 4;
  const int wm = wave >> 1, wn = wave & 1;
  const long m0 = (long)blockIdx.y * 128;
  const long n0 = (long)blockIdx.x * 128;
  const int srow = t >> 3, sc8 = t & 7;   // staging: row = i*32+srow, col8 = sc8

  const bf16_t* Ag = A + (m0 + srow) * LD + sc8 * 8;
  const bf16_t* Bg = Bm + (n0 + srow) * LD + sc8 * 8;

  f32x4 acc[4][4] = {};
  const int nk = LD >> 6;
  for (int kt = 0; kt < nk; ++kt) {
    const long koff = (long)kt * 64;
    __syncthreads();   // previous tile's compute done before overwrite
#pragma unroll
    for (int i = 0; i < 4; ++i) {
      __builtin_amdgcn_global_load_lds(
          (const __attribute__((address_space(1))) uint32_t*)(const void*)(Ag + (long)i * 32 * LD + koff),
          (__attribute__((address_space(3))) uint32_t*)(void*)(&As[(i * 256 + t) * 8]),
          16, 0, 0);
      __builtin_amdgcn_global_load_lds(
          (const __attribute__((address_space(1))) uint32_t*)(const void*)(Bg + (long)i * 32 * LD + koff),
          (__attribute__((address_space(3))) uint32_t*)(void*)(&Bs[(i * 256 + t) * 8]),
          16, 0, 0);
    }
    __syncthreads();   // compiler drains vmcnt(0) before this barrier
#pragma unroll
    for (int kk = 0; kk < 2; ++kk) {
      bf16x8 af[4], bfr[4];
#pragma unroll
      for (int mi = 0; mi < 4; ++mi)
        af[mi] = *reinterpret_cast<const bf16x8*>(
            &As[(wm * 64 + mi * 16 + c) * 64 + kk * 32 + g * 8]);
#pragma unroll
      for (int ni = 0; ni < 4; ++ni)
        bfr[ni] = *reinterpret_cast<const bf16x8*>(
            &Bs[(wn * 64 + ni * 16 + c) * 64 + kk * 32 + g * 8]);
#pragma unroll
      for (int mi = 0; mi < 4; ++mi)
#pragma unroll
        for (int ni = 0; ni < 4; ++ni)
          acc[mi][ni] = __builtin_amdgcn_mfma_f32_16x16x32_bf16(
              af[mi], bfr[ni], acc[mi][ni], 0, 0, 0);
    }
  }
  // C/D layout: col = lane&15, row = (lane>>4)*4 + r
#pragma unroll
  for (int mi = 0; mi < 4; ++mi)
#pragma unroll
    for (int ni = 0; ni < 4; ++ni)
#pragma unroll
      for (int r = 0; r < 4; ++r) {
        long m = m0 + wm * 64 + mi * 16 + 4 * g + r;
        long n = n0 + wn * 64 + ni * 16 + c;
        C[m * N + n] = (CT)acc[mi][ni][r];
      }
}

// ---------------- fused RMSNorm + RoPE + [B,S,h,D]->[B,h,S,D] transpose ----------------
__global__ __launch_bounds__(256) void k_nr(
    const bf16_t* __restrict__ raw, bf16_t* __restrict__ outp,
    const float* __restrict__ w, const float* __restrict__ cosb,
    const float* __restrict__ sinb, int nheads, int rstride) {
  const int wid = (blockIdx.x * 256 + threadIdx.x) >> 6;
  const int lane = threadIdx.x & 63;
  const int h = wid % nheads;
  const int bs = wid / nheads;           // b*S + s
  const int b = bs / SS, s = bs - b * SS;
  const bf16_t* rp = raw + (long)bs * rstride + h * DD;
  float x0 = (float)rp[lane];
  float x1 = (float)rp[lane + 64];
  float ssq = x0 * x0 + x1 * x1;
#pragma unroll
  for (int m = 1; m < 64; m <<= 1) ssq += __shfl_xor(ssq, m);
  const float rs = rsqrtf(ssq * (1.0f / DD) + 1e-6f);
  const float xn0 = x0 * rs * w[lane];
  const float xn1 = x1 * rs * w[lane + 64];
  const float cc = cosb[(long)bs * DD + lane];   // cos[d+64]==cos[d]
  const float sn = sinb[(long)bs * DD + lane];
  bf16_t o0 = (bf16_t)(xn0 * cc - xn1 * sn);
  bf16_t o1 = (bf16_t)(xn1 * cc + xn0 * sn);
  bf16_t* op = outp + (((long)b * nheads + h) * SS + s) * DD;
  op[lane] = o0;
  op[lane + 64] = o1;
}

// ---------------- V transpose -> TILED V^T: [B][kvh][S/64][128 d][64 k] ----------------
// per block: one 64-key x 128-d tile; coalesced in, LDS transpose,
// 16KB fully-contiguous tile out (no 4KB-stride DRAM aliasing).
__global__ __launch_bounds__(256) void k_vt(const bf16_t* __restrict__ src,
                                            bf16_t* __restrict__ vt) {
  __shared__ bf16_t Ls[64 * 136];   // pad 128->136
  const int t = threadIdx.x;
  const int s0 = blockIdx.x * 64;
  const int kvh = blockIdx.y;
  const int b = blockIdx.z;
  const bf16_t* ip = src + ((long)b * SS) * 4096 + 3072 + kvh * DD;
#pragma unroll
  for (int i = 0; i < 4; ++i) {
    const int cid = i * 256 + t;
    const int sr = cid >> 4, c8 = cid & 15;
    *reinterpret_cast<uint4*>(&Ls[sr * 136 + c8 * 8]) =
        *reinterpret_cast<const uint4*>(ip + (long)(s0 + sr) * 4096 + c8 * 8);
  }
  __syncthreads();
  const int d = t >> 1, sh = (t & 1) * 32;
  bf16_t* op = vt + (((long)b * NKVH + kvh) * 32 + (s0 >> 6)) * 8192 + d * 64 + sh;
  bf16_t buf[32];
#pragma unroll
  for (int j = 0; j < 32; ++j) buf[j] = Ls[(sh + j) * 136 + d];
#pragma unroll
  for (int q = 0; q < 4; ++q)
    reinterpret_cast<uint4*>(op)[q] = reinterpret_cast<uint4*>(buf)[q];
}

// ---------------- causal GQA flash attention v5 ----------------
// 4 waves x 32 q rows (Q-tile 128); KVBLK=64. K: [64][128] XOR-swizzled.
// V: tile-contiguous global V^T (16KB/tile, sequential) -> Vs[128][64] swizzled.
// P^T: per-wave XOR-swizzled LDS.
__global__ __launch_bounds__(256, 2) void k_attn(
    const bf16_t* __restrict__ Qh, const bf16_t* __restrict__ Kh,
    const bf16_t* __restrict__ VT, bf16_t* __restrict__ AO) {
  __shared__ bf16_t Ks[64 * 128];          // 16 KB, swizzled
  __shared__ bf16_t Vs[128 * 64];          // 16 KB, V^T rows, swizzled
  __shared__ bf16_t Pq[4 * 2 * 16 * 64];   // 16 KB, per-wave P
  const int t = threadIdx.x;
  const int lane = t & 63, wave = t >> 6;
  const int c = lane & 15, g = lane >> 4;

  // grid remap: xcd-grouped heads + complementary qt pairing (id, id+256)
  const int id = blockIdx.x;
  const int xcd = id & 7, j2 = (id >> 3) & 3, qt8 = (id >> 5) & 7, half = id >> 8;
  const int qt = half ? (15 - qt8) : qt8;
  const int hb = xcd * 4 + j2;
  const int h = hb & 15, b = hb >> 4;
  const int kvh = h >> 1;                  // GQA n_rep = 2

  const int qbase = qt * 128 + wave * 32;
  const int qg0 = qbase + c, qg1 = qbase + 16 + c;

  const bf16_t* qp = Qh + (((long)b * NHEAD + h) * SS) * DD;
  bf16x8 qf[2][4];
#pragma unroll
  for (int qc = 0; qc < 2; ++qc)
#pragma unroll
    for (int kb = 0; kb < 4; ++kb)
      qf[qc][kb] = *reinterpret_cast<const bf16x8*>(
          qp + (long)(qbase + qc * 16 + c) * DD + kb * 32 + g * 8);

  const bf16_t* kp = Kh + ((long)b * NKVH + kvh) * SS * DD;
  const bf16_t* vtp = VT + ((long)b * NKVH + kvh) * 32 * 8192;   // tiled

  f32x4 o[8][2] = {};
  float mrow[2] = {-1e30f, -1e30f}, lrow[2] = {0.f, 0.f};
  const int srow2 = t >> 4, sc16 = t & 15;
  const int kv_end = qt * 128 + 128;
  const float scale = 0.08838834764831845f;   // 1/sqrt(128)
  const int c7x8 = 8 * (c & 7);

  for (int kv0 = 0; kv0 < kv_end; kv0 += 64) {
    __syncthreads();
    // stage K [64 keys][128 d], XOR-swizzled, b128
#pragma unroll
    for (int rr = 0; rr < 4; ++rr) {
      const int row = srow2 + rr * 16;
      uint4 kvv = *reinterpret_cast<const uint4*>(kp + (long)(kv0 + row) * DD + sc16 * 8);
      *reinterpret_cast<uint4*>(&Ks[row * 128 + 8 * (sc16 ^ (row & 7))]) = kvv;
    }
    // stage V^T tile (16KB contiguous) -> Vs[128 d][64 k], XOR-swizzled
    {
      const bf16_t* tb = vtp + (kv0 >> 6) * 8192;
#pragma unroll
      for (int i = 0; i < 4; ++i) {
        const int cid = i * 256 + t;
        const int d = cid >> 3, c8 = cid & 7;
        uint4 vv = *reinterpret_cast<const uint4*>(tb + cid * 8);
        *reinterpret_cast<uint4*>(&Vs[d * 64 + 8 * (c8 ^ (d & 7))]) = vv;
      }
    }
    __syncthreads();

    if (kv0 <= qbase + 31) {      // wave-uniform: skip fully-masked tiles
      // ---- S^T = K·Q^T ----
      f32x4 s[2][4] = {};
#pragma unroll
      for (int kb = 0; kb < 4; ++kb) {
        bf16x8 kf[4];
#pragma unroll
        for (int kc = 0; kc < 4; ++kc)
          kf[kc] = *reinterpret_cast<const bf16x8*>(
              &Ks[(kc * 16 + c) * 128 + 8 * (((kb << 2) | g) ^ (c & 7))]);
#pragma unroll
        for (int qc = 0; qc < 2; ++qc)
#pragma unroll
          for (int kc = 0; kc < 4; ++kc)
            s[qc][kc] = __builtin_amdgcn_mfma_f32_16x16x32_bf16(
                kf[kc], qf[qc][kb], s[qc][kc], 0, 0, 0);
      }
      // ---- online softmax (per qc), P^T -> per-wave LDS ----
#pragma unroll
      for (int qc = 0; qc < 2; ++qc) {
        const int qg = qc ? qg1 : qg0;
        float sv[16];
#pragma unroll
        for (int i = 0; i < 16; ++i) {
          const int key = kv0 + (i >> 2) * 16 + 4 * g + (i & 3);
          const float x = s[qc][i >> 2][i & 3];
          sv[i] = (key <= qg) ? x * scale : -1e30f;
        }
        float vm = sv[0];
#pragma unroll
        for (int i = 1; i < 16; ++i) vm = fmaxf(vm, sv[i]);
        vm = fmaxf(vm, __shfl_xor(vm, 16));
        vm = fmaxf(vm, __shfl_xor(vm, 32));
        const float mnew = fmaxf(mrow[qc], vm);
        const float alpha = __expf(mrow[qc] - mnew);
        float p[16], ps = 0.f;
#pragma unroll
        for (int i = 0; i < 16; ++i) { p[i] = __expf(sv[i] - mnew); ps += p[i]; }
        ps += __shfl_xor(ps, 16);
        ps += __shfl_xor(ps, 32);
        lrow[qc] = lrow[qc] * alpha + ps;
        mrow[qc] = mnew;
#pragma unroll
        for (int dt = 0; dt < 8; ++dt) o[dt][qc] = o[dt][qc] * alpha;
#pragma unroll
        for (int kc = 0; kc < 4; ++kc) {
          bf16x4 pk;
#pragma unroll
          for (int r = 0; r < 4; ++r) pk[r] = (bf16_t)p[kc * 4 + r];
          *reinterpret_cast<bf16x4*>(
              &Pq[((wave * 2 + qc) * 16 + c) * 64 + ((kc * 16 + 4 * g) ^ c7x8)]) = pk;
        }
      }
      // ---- O^T += V^T · P^T ----
#pragma unroll
      for (int kc2 = 0; kc2 < 2; ++kc2) {
        bf16x8 pf[2];
#pragma unroll
        for (int qc = 0; qc < 2; ++qc)
          pf[qc] = *reinterpret_cast<const bf16x8*>(
              &Pq[((wave * 2 + qc) * 16 + c) * 64 + ((kc2 * 32 + g * 8) ^ c7x8)]);
#pragma unroll
        for (int dt = 0; dt < 8; ++dt) {
          const int dr = dt * 16 + c;
          bf16x8 vf = *reinterpret_cast<const bf16x8*>(
              &Vs[dr * 64 + 8 * ((kc2 * 4 + g) ^ (c & 7))]);
#pragma unroll
          for (int qc = 0; qc < 2; ++qc)
            o[dt][qc] = __builtin_amdgcn_mfma_f32_16x16x32_bf16(
                vf, pf[qc], o[dt][qc], 0, 0, 0);
        }
      }
    }
  }
  // ---- epilogue ----
#pragma unroll
  for (int qc = 0; qc < 2; ++qc) {
    const float linv = 1.0f / lrow[qc];
    bf16_t* aop = AO + ((long)(b * SS) + qbase + qc * 16 + c) * (NHEAD * DD) + h * DD;
#pragma unroll
    for (int dt = 0; dt < 8; ++dt) {
      bf16x4 ov;
#pragma unroll
      for (int r = 0; r < 4; ++r) ov[r] = (bf16_t)(o[dt][qc][r] * linv);
      *reinterpret_cast<bf16x4*>(aop + dt * 16 + 4 * g) = ov;
    }
  }
}

// ---------------- launch ----------------
extern "C" void kernel_launch(void* const* d_in, const int* in_sizes, int n_in,
                              void* d_out, int out_size, void* d_ws, size_t ws_size,
                              hipStream_t stream) {
  const float* hidden = (const float*)d_in[0];
  const float* cosb   = (const float*)d_in[1];
  const float* sinb   = (const float*)d_in[2];
  const float* Wq     = (const float*)d_in[3];
  const float* Wk     = (const float*)d_in[4];
  const float* Wv     = (const float*)d_in[5];
  const float* Wo     = (const float*)d_in[6];
  const float* qnw    = (const float*)d_in[7];
  const float* knw    = (const float*)d_in[8];
  float* outp = (float*)d_out;
  char* ws = (char*)d_ws;
  const size_t MB = 1024 * 1024;
  bf16_t* hbf   = (bf16_t*)(ws + 0);        //  8 MB  hidden bf16 [4096][1024]
  bf16_t* wqkv  = (bf16_t*)(ws + 8 * MB);   //  8 MB  [Wq;Wk;Wv] as [4096][1024]
  bf16_t* wob   = (bf16_t*)(ws + 16 * MB);  //  4 MB
  bf16_t* qkvr  = (bf16_t*)(ws + 20 * MB);  // 32 MB  [4096][4096] fused QKV out
  bf16_t* qn    = (bf16_t*)(ws + 52 * MB);  // 16 MB  [B,NH,S,D]
  bf16_t* kn    = (bf16_t*)(ws + 68 * MB);  //  8 MB  [B,NKV,S,D]
  bf16_t* vt    = (bf16_t*)(ws + 76 * MB);  //  8 MB  tiled V^T  (total 84 MB)
  bf16_t* ao    = qkvr;                     // reuse (16 MB needed)

  k_cvt_all<<<2048, 256, 0, stream>>>(hidden, Wq, Wk, Wv, Wo, hbf, wqkv, wob);

  // fused QKV projection: C[4096][4096] = hbf[4096][1024] x wqkv^T
  k_gemm_lds<bf16_t><<<dim3(32, 32), 256, 0, stream>>>(hbf, wqkv, qkvr, MM, 4096, 1024);

  k_nr<<<MM * NHEAD / 4, 256, 0, stream>>>(qkvr, qn, qnw, cosb, sinb, NHEAD, 4096);
  k_nr<<<MM * NKVH / 4, 256, 0, stream>>>(qkvr + 2048, kn, knw, cosb, sinb, NKVH, 4096);
  k_vt<<<dim3(32, 8, 2), 256, 0, stream>>>(qkvr, vt);

  k_attn<<<dim3(512), 256, 0, stream>>>(qn, kn, vt, ao);

  // output projection (fp32 out, plain store)
  k_gemm_lds<float><<<dim3(8, 32), 256, 0, stream>>>(ao, wob, outp, MM, 1024, 2048);
}